// Round 3
// baseline (154.397 us; speedup 1.0000x reference)
//
#include <hip/hip_runtime.h>

// SoftAttention: B=4, Q=64, S=1024, H=512, fp32.
// out = [context (B*Q*H)] ++ [weights (B*Q*S)]
// ws layout: Eq [256*512]f32 @0; Ek [4096*512]f32 @+512KB; part aliases Ek;
//            Bhi/Blo (bf16 hi/lo of W, granule-major) @+8.5MB (1MB each);
//            Xhi/Xlo (bf16 hi/lo of X, granule-major) after (4.25MB each).
//
// R1: proj on MFMA via bf16 3-product hi/lo split.
// R2: score exp-factoring: Eq=exp(2(q+b)), Ek=exp(2(k+b)); score = wsum
//     - 2*sum_h we_h * rcp(1+Eq*Ek) with lane=s layout; rcps paired.
// R3: (a) X pre-converted ONCE (convert_x) -> proj staging is pure copies
//     (was: 8x-redundant fp32->bf16 split per ct-block, ~15us VALU);
//     (b) proj 128x64 tiles, 512thr/8 waves, 12 MFMA/wave-step;
//     (c) score reads w/q rows as wave-uniform scalar loads (K$), LDS only
//     holds Ek -> LDS traffic 1.07GB -> 268MB.

constexpr int kB = 4;
constexpr int kQ = 64;
constexpr int kS = 1024;
constexpr int kH = 512;

typedef short bf16x8 __attribute__((ext_vector_type(8)));
typedef float f32x4 __attribute__((ext_vector_type(4)));

__device__ __forceinline__ unsigned bf16rtn_bits(float x) {
  unsigned u = __float_as_uint(x);
  u += 0x7FFFu + ((u >> 16) & 1u);
  return u;  // hi bf16 = u>>16; its f32 bits = u & 0xFFFF0000
}

// ---------------------------------------------------------------------------
// W converter: Wk/Wq [512][512] fp32 -> bf16 hi/lo, granule-major:
// granule gid = ((mat*8 + ct)*16 + kt)*256 + (g*64 + c), holding
// W[kt*32 + g*8 + j][ct*64 + c] for j=0..7.
// ---------------------------------------------------------------------------
__global__ __launch_bounds__(256) void convert_w(
    const float* __restrict__ Wk, const float* __restrict__ Wq,
    unsigned short* __restrict__ Bhi, unsigned short* __restrict__ Blo) {
  const int gid = blockIdx.x * 256 + threadIdx.x;
  const int c = gid & 63;
  const int g = (gid >> 6) & 3;
  const int kt = (gid >> 8) & 15;
  const int ct = (gid >> 12) & 7;
  const int mat = gid >> 15;
  const float* W = mat ? Wq : Wk;
  const float* src = W + (size_t)(kt * 32 + g * 8) * kH + ct * 64 + c;
  bf16x8 hv, lv;
#pragma unroll
  for (int j = 0; j < 8; j++) {
    float x = src[(size_t)j * kH];
    unsigned u = bf16rtn_bits(x);
    float hf = __uint_as_float(u & 0xFFFF0000u);
    unsigned v = bf16rtn_bits(x - hf);
    hv[j] = (short)(u >> 16);
    lv[j] = (short)(v >> 16);
  }
  *(bf16x8*)(Bhi + (size_t)gid * 8) = hv;
  *(bf16x8*)(Blo + (size_t)gid * 8) = lv;
}

// ---------------------------------------------------------------------------
// X converter: key_ (4096 rows) ++ query (256 rows) -> bf16 hi/lo,
// granule-major per (rt 0..33, kt 0..15): slot s = g*128 + r holds
// X[rt*128 + r][kt*32 + g*8 + j], j=0..7.  LDS transpose for coalescing.
// grid = (16 kt, 34 rt), 256 thr.
// ---------------------------------------------------------------------------
__global__ __launch_bounds__(256) void convert_x(
    const float* __restrict__ key_, const float* __restrict__ query,
    unsigned short* __restrict__ Xhi, unsigned short* __restrict__ Xlo) {
  __shared__ __align__(16) unsigned short LHi[128 * 40];  // pad 40 (16B-aligned rows)
  __shared__ __align__(16) unsigned short LLo[128 * 40];
  const int kt = blockIdx.x;
  const int rt = blockIdx.y;
  const float* X = (rt < 32) ? (key_ + (size_t)rt * 128 * kH)
                             : (query + (size_t)(rt - 32) * 128 * kH);
  const int t = threadIdx.x;
  const int r = t >> 1, c0 = (t & 1) * 16;
  const float* src = X + (size_t)r * kH + kt * 32 + c0;
  bf16x8 hv0, hv1, lv0, lv1;
#pragma unroll
  for (int i = 0; i < 16; i++) {
    float x = src[i];
    unsigned u = bf16rtn_bits(x);
    float hf = __uint_as_float(u & 0xFFFF0000u);
    unsigned v = bf16rtn_bits(x - hf);
    if (i < 8) { hv0[i] = (short)(u >> 16); lv0[i] = (short)(v >> 16); }
    else       { hv1[i - 8] = (short)(u >> 16); lv1[i - 8] = (short)(v >> 16); }
  }
  *(bf16x8*)&LHi[r * 40 + c0] = hv0;
  *(bf16x8*)&LHi[r * 40 + c0 + 8] = hv1;
  *(bf16x8*)&LLo[r * 40 + c0] = lv0;
  *(bf16x8*)&LLo[r * 40 + c0 + 8] = lv1;
  __syncthreads();
  const size_t obase = (size_t)(rt * 16 + kt) * 512 * 8;
#pragma unroll
  for (int p = 0; p < 2; p++) {
    const int s = t + p * 256;
    const int rr = s & 127, g = s >> 7;
    *(uint4*)(Xhi + obase + (size_t)s * 8) = *(const uint4*)&LHi[rr * 40 + g * 8];
    *(uint4*)(Xlo + obase + (size_t)s * 8) = *(const uint4*)&LLo[rr * 40 + g * 8];
  }
}

// ---------------------------------------------------------------------------
// Projection via MFMA: E = exp(2*(X[4352,512] @ W[512,512] + bias)).
// 128x64 tile, 512 thr = 8 waves (4 m-quarters x 2 n-halves), each wave
// 32x32 out = 2x2 16x16 frags, 3 products each = 12 MFMA/step. BK=32,
// double-buffered LDS (48KB), pure-copy staging (X/W pre-converted).
// grid = (8 ct, 34 rt: 32 Ek + 2 Eq).
// ---------------------------------------------------------------------------
__global__ __launch_bounds__(512) void proj_mfma(
    const unsigned short* __restrict__ Xhi, const unsigned short* __restrict__ Xlo,
    const unsigned short* __restrict__ Bhi, const unsigned short* __restrict__ Blo,
    const float* __restrict__ bk, const float* __restrict__ bq,
    float* __restrict__ Ek, float* __restrict__ Eq) {
  __shared__ __align__(16) unsigned short AhiL[2][4096];  // 512 slots x 8
  __shared__ __align__(16) unsigned short AloL[2][4096];
  __shared__ __align__(16) unsigned short BhiL[2][2048];  // 256 slots x 8
  __shared__ __align__(16) unsigned short BloL[2][2048];

  const int ct = blockIdx.x;
  const int rt = blockIdx.y;  // 0..33
  const int mat = (rt >= 32) ? 1 : 0;
  const float* bias = mat ? bq : bk;
  float* Y = mat ? (Eq + (size_t)(rt - 32) * 128 * kH)
                 : (Ek + (size_t)rt * 128 * kH);

  const int t = threadIdx.x;
  const unsigned short* ah_src = Xhi + ((size_t)(rt * 16) * 512 + t) * 8;
  const unsigned short* al_src = Xlo + ((size_t)(rt * 16) * 512 + t) * 8;
  const int bslot = t & 255;
  const unsigned short* b_src =
      ((t < 256) ? Bhi : Blo) + ((size_t)((mat * 8 + ct) * 16) * 256 + bslot) * 8;

  uint4 pah, pal, pb;
  auto gload = [&](int kt2) {
    pah = *(const uint4*)(ah_src + (size_t)kt2 * 512 * 8);
    pal = *(const uint4*)(al_src + (size_t)kt2 * 512 * 8);
    pb = *(const uint4*)(b_src + (size_t)kt2 * 256 * 8);
  };
  auto lwrite = [&](int buf) {
    *(uint4*)&AhiL[buf][t * 8] = pah;
    *(uint4*)&AloL[buf][t * 8] = pal;
    if (t < 256) *(uint4*)&BhiL[buf][bslot * 8] = pb;
    else         *(uint4*)&BloL[buf][bslot * 8] = pb;
  };

  const int l = t & 63, lg = l >> 4, lr = l & 15;
  const int wv = t >> 6, wm = wv & 3, wn = wv >> 2;

  f32x4 acc[2][2];
#pragma unroll
  for (int m = 0; m < 2; m++)
#pragma unroll
    for (int n = 0; n < 2; n++) acc[m][n] = {0.f, 0.f, 0.f, 0.f};

  gload(0);
  lwrite(0);
  __syncthreads();

  for (int kt2 = 0; kt2 < 16; kt2++) {
    if (kt2 < 15) gload(kt2 + 1);

    const unsigned short* Ah = AhiL[kt2 & 1];
    const unsigned short* Al = AloL[kt2 & 1];
    const unsigned short* Bh = BhiL[kt2 & 1];
    const unsigned short* Bl = BloL[kt2 & 1];
    bf16x8 ah[2], al[2], bh[2], bl[2];
#pragma unroll
    for (int m = 0; m < 2; m++) {
      const int off = (lg * 128 + wm * 32 + m * 16 + lr) * 8;
      ah[m] = *(const bf16x8*)(Ah + off);
      al[m] = *(const bf16x8*)(Al + off);
    }
#pragma unroll
    for (int n = 0; n < 2; n++) {
      const int off = (lg * 64 + wn * 32 + n * 16 + lr) * 8;
      bh[n] = *(const bf16x8*)(Bh + off);
      bl[n] = *(const bf16x8*)(Bl + off);
    }
#pragma unroll
    for (int m = 0; m < 2; m++)
#pragma unroll
      for (int n = 0; n < 2; n++) {
        acc[m][n] = __builtin_amdgcn_mfma_f32_16x16x32_bf16(ah[m], bh[n], acc[m][n], 0, 0, 0);
        acc[m][n] = __builtin_amdgcn_mfma_f32_16x16x32_bf16(al[m], bh[n], acc[m][n], 0, 0, 0);
        acc[m][n] = __builtin_amdgcn_mfma_f32_16x16x32_bf16(ah[m], bl[n], acc[m][n], 0, 0, 0);
      }

    if (kt2 < 15) {
      __syncthreads();
      lwrite((kt2 + 1) & 1);
      __syncthreads();
    }
  }

  // Epilogue: E = exp(2*(acc + bias)). C/D: col = lr, row = lg*4 + jj.
  const int col0 = ct * 64 + wn * 32 + lr;
  const float b0 = bias[col0];
  const float b1 = bias[col0 + 16];
#pragma unroll
  for (int m = 0; m < 2; m++) {
    const int row0 = wm * 32 + m * 16 + lg * 4;
#pragma unroll
    for (int jj = 0; jj < 4; jj++) {
      float* y = Y + (size_t)(row0 + jj) * kH;
      y[col0]      = __expf(2.f * (acc[m][0][jj] + b0));
      y[col0 + 16] = __expf(2.f * (acc[m][1][jj] + b1));
    }
  }
}

// ---------------------------------------------------------------------------
// Scores -> sout[bq][s], lane = s, loop h.  score = wsum - 2*acc where
// acc = sum_h we_h * rcp(1 + Eq*Ek), rcps paired:
// w0/a + w1/b = (w0*b + w1*a) * rcp(a*b).
// w and Eq rows are wave-uniform -> scalar loads (K$); LDS holds only Ek.
// grid = (8 qt, 16 st, 4 b); 256 thr = 4 waves, wave = 2 q x 64 s.
// ---------------------------------------------------------------------------
__global__ __launch_bounds__(256) void score_kernel(
    const float* __restrict__ Eq, const float* __restrict__ Ek,
    const float* __restrict__ we, float* __restrict__ sout) {
  __shared__ __align__(16) float EkL[2][64 * 64];

  const int qt = blockIdx.x, st = blockIdx.y, b = blockIdx.z;
  const int t = threadIdx.x, lane = t & 63;
  const int wvu = __builtin_amdgcn_readfirstlane(t >> 6);  // uniform wave id
  const int s0 = st * 64;
  const int q0g = b * kQ + qt * 8;
  const int qA = wvu * 2;

  // wsum = sum we
  const float4* we4 = (const float4*)we;
  {
  }
  float4 u0 = we4[lane * 2], u1 = we4[lane * 2 + 1];
  float wsum = u0.x + u0.y + u0.z + u0.w + u1.x + u1.y + u1.z + u1.w;
#pragma unroll
  for (int off = 32; off; off >>= 1) wsum += __shfl_xor(wsum, off);

  // uniform row pointers (scalar-loadable)
  const float4* qa4 = (const float4*)(Eq + (size_t)(q0g + qA) * kH);
  const float4* qb4 = (const float4*)(Eq + (size_t)(q0g + qA + 1) * kH);

  // Ek staging: thread t -> row er = t>>4 (+16i), f4-slot ej = t&15;
  // slot swizzle ej ^ (row & 15).
  const int er = t >> 4;
  const int ej = t & 15;
  const float* ekg = Ek + (size_t)(b * kS + s0 + er) * kH + ej * 4;
  float4 pk[4];
  auto gload = [&](int c) {
#pragma unroll
    for (int i = 0; i < 4; i++)
      pk[i] = *(const float4*)(ekg + (size_t)(16 * i) * kH + c * 64);
  };
  auto lwrite = [&](int buf) {
#pragma unroll
    for (int i = 0; i < 4; i++) {
      const int row = er + 16 * i;
      *(float4*)(&EkL[buf][row * 64 + ((ej ^ (row & 15)) << 2)]) = pk[i];
    }
  };

  gload(0);
  lwrite(0);
  __syncthreads();

  float accA = 0.f, accB = 0.f;
  const int sw = lane & 15;

  for (int c = 0; c < 8; c++) {
    if (c < 7) gload(c + 1);
    const float* ekb = &EkL[c & 1][lane * 64];
#pragma unroll 4
    for (int g = 0; g < 16; g++) {
      float4 ek = *(const float4*)(ekb + ((g ^ sw) << 2));
      float4 w = we4[c * 16 + g];     // uniform -> s_load
      float4 qa = qa4[c * 16 + g];    // uniform -> s_load
      float4 qb = qb4[c * 16 + g];    // uniform -> s_load
      {
        float a1 = fmaf(qa.x, ek.x, 1.f), b1 = fmaf(qa.y, ek.y, 1.f);
        float n1 = fmaf(w.y, a1, w.x * b1);
        accA = fmaf(n1, __builtin_amdgcn_rcpf(a1 * b1), accA);
        float a2 = fmaf(qa.z, ek.z, 1.f), b2 = fmaf(qa.w, ek.w, 1.f);
        float n2 = fmaf(w.w, a2, w.z * b2);
        accA = fmaf(n2, __builtin_amdgcn_rcpf(a2 * b2), accA);
      }
      {
        float a1 = fmaf(qb.x, ek.x, 1.f), b1 = fmaf(qb.y, ek.y, 1.f);
        float n1 = fmaf(w.y, a1, w.x * b1);
        accB = fmaf(n1, __builtin_amdgcn_rcpf(a1 * b1), accB);
        float a2 = fmaf(qb.z, ek.z, 1.f), b2 = fmaf(qb.w, ek.w, 1.f);
        float n2 = fmaf(w.w, a2, w.z * b2);
        accB = fmaf(n2, __builtin_amdgcn_rcpf(a2 * b2), accB);
      }
    }
    if (c < 7) {
      __syncthreads();
      lwrite((c + 1) & 1);
      __syncthreads();
    }
  }

  sout[(size_t)(q0g + qA + 0) * kS + s0 + lane] = fmaf(-2.f, accA, wsum);
  sout[(size_t)(q0g + qA + 1) * kS + s0 + lane] = fmaf(-2.f, accB, wsum);
}

// ---------------------------------------------------------------------------
// Softmax in place on wout rows of 1024.  grid = 256 rows, 256 thr.
// ---------------------------------------------------------------------------
__global__ __launch_bounds__(256) void softmax_kernel(float* __restrict__ wout) {
  __shared__ float redm[4];
  __shared__ float reds[4];
  const int row = blockIdx.x;
  const int t = threadIdx.x, wave = t >> 6, lane = t & 63;
  float4* rp = (float4*)(wout + (size_t)row * kS);
  float4 v = rp[t];

  float m = fmaxf(fmaxf(v.x, v.y), fmaxf(v.z, v.w));
#pragma unroll
  for (int off = 32; off; off >>= 1) m = fmaxf(m, __shfl_xor(m, off));
  if (lane == 0) redm[wave] = m;
  __syncthreads();
  m = fmaxf(fmaxf(redm[0], redm[1]), fmaxf(redm[2], redm[3]));

  float4 e;
  e.x = __expf(v.x - m); e.y = __expf(v.y - m);
  e.z = __expf(v.z - m); e.w = __expf(v.w - m);
  float sum = e.x + e.y + e.z + e.w;
#pragma unroll
  for (int off = 32; off; off >>= 1) sum += __shfl_xor(sum, off);
  if (lane == 0) reds[wave] = sum;
  __syncthreads();
  sum = reds[0] + reds[1] + reds[2] + reds[3];
  float inv = 1.f / sum;
  e.x *= inv; e.y *= inv; e.z *= inv; e.w *= inv;
  rp[t] = e;
}

// ---------------------------------------------------------------------------
// Context partials: part[sc][bq][h] = sum_{s in chunk} w[bq][s] * value[b][s][h]
// grid = 256 (b x 2 h-chunks x 4 q-chunks x 8 s-chunks), 256 thr.
// ---------------------------------------------------------------------------
__global__ __launch_bounds__(256) void context_kernel(
    const float* __restrict__ wout, const float* __restrict__ value,
    float* __restrict__ part) {
  __shared__ __align__(16) float wt[128][16];
  const int bx = blockIdx.x;
  const int sc = bx & 7, qc = (bx >> 3) & 3, hc = (bx >> 5) & 1, b = bx >> 6;
  const int t = threadIdx.x;
  const int s0 = sc * 128, q0 = qc * 16;

  {
    const int q_l = t & 15;
    const int sseg = (t >> 4) * 8;
    const float4* p4 =
        (const float4*)(wout + (size_t)(b * kQ + q0 + q_l) * kS + s0 + sseg);
    float4 u0 = p4[0], u1 = p4[1];
    wt[sseg + 0][q_l] = u0.x; wt[sseg + 1][q_l] = u0.y;
    wt[sseg + 2][q_l] = u0.z; wt[sseg + 3][q_l] = u0.w;
    wt[sseg + 4][q_l] = u1.x; wt[sseg + 5][q_l] = u1.y;
    wt[sseg + 6][q_l] = u1.z; wt[sseg + 7][q_l] = u1.w;
  }
  __syncthreads();

  const int h = hc * 256 + t;
  const float* vb = value + ((size_t)b * kS + s0) * kH + h;
  float acc[16];
#pragma unroll
  for (int i = 0; i < 16; i++) acc[i] = 0.f;

#pragma unroll 4
  for (int s = 0; s < 128; s++) {
    float v = vb[(size_t)s * kH];
    const float4* wrow = (const float4*)&wt[s][0];
    float4 a0 = wrow[0], a1 = wrow[1], a2 = wrow[2], a3 = wrow[3];
    acc[0]  = fmaf(a0.x, v, acc[0]);  acc[1]  = fmaf(a0.y, v, acc[1]);
    acc[2]  = fmaf(a0.z, v, acc[2]);  acc[3]  = fmaf(a0.w, v, acc[3]);
    acc[4]  = fmaf(a1.x, v, acc[4]);  acc[5]  = fmaf(a1.y, v, acc[5]);
    acc[6]  = fmaf(a1.z, v, acc[6]);  acc[7]  = fmaf(a1.w, v, acc[7]);
    acc[8]  = fmaf(a2.x, v, acc[8]);  acc[9]  = fmaf(a2.y, v, acc[9]);
    acc[10] = fmaf(a2.z, v, acc[10]); acc[11] = fmaf(a2.w, v, acc[11]);
    acc[12] = fmaf(a3.x, v, acc[12]); acc[13] = fmaf(a3.y, v, acc[13]);
    acc[14] = fmaf(a3.z, v, acc[14]); acc[15] = fmaf(a3.w, v, acc[15]);
  }

  float* pp = part + (size_t)sc * kB * kQ * kH;
#pragma unroll
  for (int i = 0; i < 16; i++)
    pp[(size_t)(b * kQ + q0 + i) * kH + h] = acc[i];
}

// ctx[i] = sum over 8 s-chunk partials
__global__ __launch_bounds__(256) void reduce_kernel(
    const float* __restrict__ part, float* __restrict__ ctx) {
  const int i = blockIdx.x * 256 + threadIdx.x;
  float4 a = {0, 0, 0, 0};
#pragma unroll
  for (int p = 0; p < 8; p++) {
    float4 v = ((const float4*)(part + (size_t)p * kB * kQ * kH))[i];
    a.x += v.x; a.y += v.y; a.z += v.z; a.w += v.w;
  }
  ((float4*)ctx)[i] = a;
}

extern "C" void kernel_launch(void* const* d_in, const int* in_sizes, int n_in,
                              void* d_out, int out_size, void* d_ws,
                              size_t ws_size, hipStream_t stream) {
  const float* query = (const float*)d_in[0];
  const float* key_  = (const float*)d_in[1];
  const float* value = (const float*)d_in[2];
  const float* Wq    = (const float*)d_in[3];
  const float* bq    = (const float*)d_in[4];
  const float* Wk    = (const float*)d_in[5];
  const float* bk    = (const float*)d_in[6];
  const float* we    = (const float*)d_in[7];
  // be (d_in[8]) cancels in softmax.

  float* ctx  = (float*)d_out;                         // [256*512]
  float* wout = (float*)d_out + (size_t)kB * kQ * kH;  // [256*1024]

  float* Eq   = (float*)d_ws;                          // 512 KB
  float* Ek   = Eq + (size_t)kB * kQ * kH;             // 8 MB
  float* part = Ek;                                    // aliases Ek (dead after score)
  unsigned short* Bhi =
      (unsigned short*)((char*)d_ws + (size_t)(kB * kQ * kH + kB * kS * kH) * 4);
  unsigned short* Blo = Bhi + (size_t)2 * 8 * 16 * 256 * 8;  // +1MB
  unsigned short* Xhi = Blo + (size_t)2 * 8 * 16 * 256 * 8;  // +1MB
  unsigned short* Xlo = Xhi + (size_t)34 * 16 * 512 * 8;     // +4.25MB

  convert_w<<<256, 256, 0, stream>>>(Wk, Wq, Bhi, Blo);
  convert_x<<<dim3(16, 34), 256, 0, stream>>>(key_, query, Xhi, Xlo);
  proj_mfma<<<dim3(8, 34), 512, 0, stream>>>(Xhi, Xlo, Bhi, Blo, bk, bq, Ek, Eq);
  score_kernel<<<dim3(8, 16, 4), 256, 0, stream>>>(Eq, Ek, we, wout);
  softmax_kernel<<<kB * kQ, 256, 0, stream>>>(wout);
  context_kernel<<<256, 256, 0, stream>>>(wout, value, part);
  reduce_kernel<<<kB * kQ * kH / 4 / 256, 256, 0, stream>>>(part, ctx);
}

// Round 4
// 148.421 us; speedup vs baseline: 1.0403x; 1.0403x over previous
//
#include <hip/hip_runtime.h>

// SoftAttention: B=4, Q=64, S=1024, H=512, fp32.
// out = [context (B*Q*H)] ++ [weights (B*Q*S)]
// ws layout: Eq [256*512]f32 @0; Ek [4096*512]f32 @+512KB;
//            Bhi/Blo (bf16 hi/lo of W, granule-major) @+8.5MB (1MB each);
//            Xhi/Xlo (bf16 hi/lo of X, granule-major) @+10.5MB (4.25MB each);
//            sraw (raw scores) @+19MB (1MB).
//
// R1: proj on MFMA via bf16 3-product hi/lo split.
// R2: score exp-factoring: Eq=exp(2(q+b)), Ek=exp(2(k+b)); score = wsum
//     - 2*sum_h we_h * rcp(1+Eq*Ek), lane=s layout, rcps paired.
// R3: X/W pre-converted once; proj 128x64 tiles 512thr; score scalar q/w loads.
// R4: LAUNCH-COUNT attack (7 -> 4 dispatches; evidence: R2->R3 kernel rewrites
//     were perf-neutral => residual is inter-kernel overhead):
//     (a) convert_w + convert_x fused into convert_all;
//     (b) softmax + context + reduce fused into ctx_fused: score writes raw
//         scores to ws; ctx block recomputes row softmax in-wave (hc==0
//         blocks write normalized wout), stages weights in LDS, accumulates
//         context over full s (no partial round-trip; value read once per
//         (b,hc) via qc-stride-16 XCD-local block ordering).

constexpr int kB = 4;
constexpr int kQ = 64;
constexpr int kS = 1024;
constexpr int kH = 512;

typedef short bf16x8 __attribute__((ext_vector_type(8)));
typedef float f32x4 __attribute__((ext_vector_type(4)));

__device__ __forceinline__ unsigned bf16rtn_bits(float x) {
  unsigned u = __float_as_uint(x);
  u += 0x7FFFu + ((u >> 16) & 1u);
  return u;  // hi bf16 = u>>16; its f32 bits = u & 0xFFFF0000
}

// ---------------------------------------------------------------------------
// Fused converter. Blocks 0..255: W -> Bhi/Blo granule-major
//   (gid = ((mat*8+ct)*16+kt)*256 + g*64+c holds W[kt*32+g*8+j][ct*64+c]).
// Blocks 256..799: X (key_ 4096 rows ++ query 256 rows) -> Xhi/Xlo
//   granule-major per (rt 0..33, kt 0..15): slot g*128+r holds
//   X[rt*128+r][kt*32+g*8+j]; LDS transpose for coalescing.
// ---------------------------------------------------------------------------
__global__ __launch_bounds__(256) void convert_all(
    const float* __restrict__ Wk, const float* __restrict__ Wq,
    const float* __restrict__ key_, const float* __restrict__ query,
    unsigned short* __restrict__ Bhi, unsigned short* __restrict__ Blo,
    unsigned short* __restrict__ Xhi, unsigned short* __restrict__ Xlo) {
  __shared__ __align__(16) unsigned short LHi[128 * 40];
  __shared__ __align__(16) unsigned short LLo[128 * 40];
  const int bid = blockIdx.x;
  const int t = threadIdx.x;
  if (bid < 256) {
    const int gid = bid * 256 + t;
    const int c = gid & 63;
    const int g = (gid >> 6) & 3;
    const int kt = (gid >> 8) & 15;
    const int ct = (gid >> 12) & 7;
    const int mat = gid >> 15;
    const float* W = mat ? Wq : Wk;
    const float* src = W + (size_t)(kt * 32 + g * 8) * kH + ct * 64 + c;
    bf16x8 hv, lv;
#pragma unroll
    for (int j = 0; j < 8; j++) {
      float x = src[(size_t)j * kH];
      unsigned u = bf16rtn_bits(x);
      float hf = __uint_as_float(u & 0xFFFF0000u);
      unsigned v = bf16rtn_bits(x - hf);
      hv[j] = (short)(u >> 16);
      lv[j] = (short)(v >> 16);
    }
    *(bf16x8*)(Bhi + (size_t)gid * 8) = hv;
    *(bf16x8*)(Blo + (size_t)gid * 8) = lv;
    return;
  }
  const int xb = bid - 256;
  const int kt = xb & 15;
  const int rt = xb >> 4;  // 0..33
  const float* X = (rt < 32) ? (key_ + (size_t)rt * 128 * kH)
                             : (query + (size_t)(rt - 32) * 128 * kH);
  const int r = t >> 1, c0 = (t & 1) * 16;
  const float* src = X + (size_t)r * kH + kt * 32 + c0;
  bf16x8 hv0, hv1, lv0, lv1;
#pragma unroll
  for (int i = 0; i < 16; i++) {
    float x = src[i];
    unsigned u = bf16rtn_bits(x);
    float hf = __uint_as_float(u & 0xFFFF0000u);
    unsigned v = bf16rtn_bits(x - hf);
    if (i < 8) { hv0[i] = (short)(u >> 16); lv0[i] = (short)(v >> 16); }
    else       { hv1[i - 8] = (short)(u >> 16); lv1[i - 8] = (short)(v >> 16); }
  }
  *(bf16x8*)&LHi[r * 40 + c0] = hv0;
  *(bf16x8*)&LHi[r * 40 + c0 + 8] = hv1;
  *(bf16x8*)&LLo[r * 40 + c0] = lv0;
  *(bf16x8*)&LLo[r * 40 + c0 + 8] = lv1;
  __syncthreads();
  const size_t obase = (size_t)(rt * 16 + kt) * 512 * 8;
#pragma unroll
  for (int p = 0; p < 2; p++) {
    const int s = t + p * 256;
    const int rr = s & 127, g = s >> 7;
    *(uint4*)(Xhi + obase + (size_t)s * 8) = *(const uint4*)&LHi[rr * 40 + g * 8];
    *(uint4*)(Xlo + obase + (size_t)s * 8) = *(const uint4*)&LLo[rr * 40 + g * 8];
  }
}

// ---------------------------------------------------------------------------
// Projection via MFMA: E = exp(2*(X[4352,512] @ W[512,512] + bias)).
// 128x64 tile, 512 thr = 8 waves (4 m x 2 n), wave = 2x2 16x16 frags,
// 3 products each = 12 MFMA/step. BK=32, double-buffered LDS (48KB),
// pure-copy staging. grid = (8 ct, 34 rt: 32 Ek + 2 Eq).
// ---------------------------------------------------------------------------
__global__ __launch_bounds__(512) void proj_mfma(
    const unsigned short* __restrict__ Xhi, const unsigned short* __restrict__ Xlo,
    const unsigned short* __restrict__ Bhi, const unsigned short* __restrict__ Blo,
    const float* __restrict__ bk, const float* __restrict__ bq,
    float* __restrict__ Ek, float* __restrict__ Eq) {
  __shared__ __align__(16) unsigned short AhiL[2][4096];
  __shared__ __align__(16) unsigned short AloL[2][4096];
  __shared__ __align__(16) unsigned short BhiL[2][2048];
  __shared__ __align__(16) unsigned short BloL[2][2048];

  const int ct = blockIdx.x;
  const int rt = blockIdx.y;  // 0..33
  const int mat = (rt >= 32) ? 1 : 0;
  const float* bias = mat ? bq : bk;
  float* Y = mat ? (Eq + (size_t)(rt - 32) * 128 * kH)
                 : (Ek + (size_t)rt * 128 * kH);

  const int t = threadIdx.x;
  const unsigned short* ah_src = Xhi + ((size_t)(rt * 16) * 512 + t) * 8;
  const unsigned short* al_src = Xlo + ((size_t)(rt * 16) * 512 + t) * 8;
  const int bslot = t & 255;
  const unsigned short* b_src =
      ((t < 256) ? Bhi : Blo) + ((size_t)((mat * 8 + ct) * 16) * 256 + bslot) * 8;

  uint4 pah, pal, pb;
  auto gload = [&](int kt2) {
    pah = *(const uint4*)(ah_src + (size_t)kt2 * 512 * 8);
    pal = *(const uint4*)(al_src + (size_t)kt2 * 512 * 8);
    pb = *(const uint4*)(b_src + (size_t)kt2 * 256 * 8);
  };
  auto lwrite = [&](int buf) {
    *(uint4*)&AhiL[buf][t * 8] = pah;
    *(uint4*)&AloL[buf][t * 8] = pal;
    if (t < 256) *(uint4*)&BhiL[buf][bslot * 8] = pb;
    else         *(uint4*)&BloL[buf][bslot * 8] = pb;
  };

  const int l = t & 63, lg = l >> 4, lr = l & 15;
  const int wv = t >> 6, wm = wv & 3, wn = wv >> 2;

  f32x4 acc[2][2];
#pragma unroll
  for (int m = 0; m < 2; m++)
#pragma unroll
    for (int n = 0; n < 2; n++) acc[m][n] = {0.f, 0.f, 0.f, 0.f};

  gload(0);
  lwrite(0);
  __syncthreads();

  for (int kt2 = 0; kt2 < 16; kt2++) {
    if (kt2 < 15) gload(kt2 + 1);

    const unsigned short* Ah = AhiL[kt2 & 1];
    const unsigned short* Al = AloL[kt2 & 1];
    const unsigned short* Bh = BhiL[kt2 & 1];
    const unsigned short* Bl = BloL[kt2 & 1];
    bf16x8 ah[2], al[2], bh[2], bl[2];
#pragma unroll
    for (int m = 0; m < 2; m++) {
      const int off = (lg * 128 + wm * 32 + m * 16 + lr) * 8;
      ah[m] = *(const bf16x8*)(Ah + off);
      al[m] = *(const bf16x8*)(Al + off);
    }
#pragma unroll
    for (int n = 0; n < 2; n++) {
      const int off = (lg * 64 + wn * 32 + n * 16 + lr) * 8;
      bh[n] = *(const bf16x8*)(Bh + off);
      bl[n] = *(const bf16x8*)(Bl + off);
    }
#pragma unroll
    for (int m = 0; m < 2; m++)
#pragma unroll
      for (int n = 0; n < 2; n++) {
        acc[m][n] = __builtin_amdgcn_mfma_f32_16x16x32_bf16(ah[m], bh[n], acc[m][n], 0, 0, 0);
        acc[m][n] = __builtin_amdgcn_mfma_f32_16x16x32_bf16(al[m], bh[n], acc[m][n], 0, 0, 0);
        acc[m][n] = __builtin_amdgcn_mfma_f32_16x16x32_bf16(ah[m], bl[n], acc[m][n], 0, 0, 0);
      }

    if (kt2 < 15) {
      __syncthreads();
      lwrite((kt2 + 1) & 1);
      __syncthreads();
    }
  }

  // Epilogue: E = exp(2*(acc + bias)). C/D: col = lr, row = lg*4 + jj.
  const int col0 = ct * 64 + wn * 32 + lr;
  const float b0 = bias[col0];
  const float b1 = bias[col0 + 16];
#pragma unroll
  for (int m = 0; m < 2; m++) {
    const int row0 = wm * 32 + m * 16 + lg * 4;
#pragma unroll
    for (int jj = 0; jj < 4; jj++) {
      float* y = Y + (size_t)(row0 + jj) * kH;
      y[col0]      = __expf(2.f * (acc[m][0][jj] + b0));
      y[col0 + 16] = __expf(2.f * (acc[m][1][jj] + b1));
    }
  }
}

// ---------------------------------------------------------------------------
// Scores -> sraw[bq][s], lane = s, loop h.  score = wsum - 2*acc where
// acc = sum_h we_h * rcp(1 + Eq*Ek), rcps paired.
// w and Eq rows are wave-uniform -> scalar loads (K$); LDS holds only Ek.
// grid = (8 qt, 16 st, 4 b); 256 thr = 4 waves, wave = 2 q x 64 s.
// ---------------------------------------------------------------------------
__global__ __launch_bounds__(256) void score_kernel(
    const float* __restrict__ Eq, const float* __restrict__ Ek,
    const float* __restrict__ we, float* __restrict__ sraw) {
  __shared__ __align__(16) float EkL[2][64 * 64];

  const int qt = blockIdx.x, st = blockIdx.y, b = blockIdx.z;
  const int t = threadIdx.x, lane = t & 63;
  const int wvu = __builtin_amdgcn_readfirstlane(t >> 6);  // uniform wave id
  const int s0 = st * 64;
  const int q0g = b * kQ + qt * 8;
  const int qA = wvu * 2;

  // wsum = sum we
  const float4* we4 = (const float4*)we;
  float4 u0 = we4[lane * 2], u1 = we4[lane * 2 + 1];
  float wsum = u0.x + u0.y + u0.z + u0.w + u1.x + u1.y + u1.z + u1.w;
#pragma unroll
  for (int off = 32; off; off >>= 1) wsum += __shfl_xor(wsum, off);

  const float4* qa4 = (const float4*)(Eq + (size_t)(q0g + qA) * kH);
  const float4* qb4 = (const float4*)(Eq + (size_t)(q0g + qA + 1) * kH);

  const int er = t >> 4;
  const int ej = t & 15;
  const float* ekg = Ek + (size_t)(b * kS + s0 + er) * kH + ej * 4;
  float4 pk[4];
  auto gload = [&](int c) {
#pragma unroll
    for (int i = 0; i < 4; i++)
      pk[i] = *(const float4*)(ekg + (size_t)(16 * i) * kH + c * 64);
  };
  auto lwrite = [&](int buf) {
#pragma unroll
    for (int i = 0; i < 4; i++) {
      const int row = er + 16 * i;
      *(float4*)(&EkL[buf][row * 64 + ((ej ^ (row & 15)) << 2)]) = pk[i];
    }
  };

  gload(0);
  lwrite(0);
  __syncthreads();

  float accA = 0.f, accB = 0.f;
  const int sw = lane & 15;

  for (int c = 0; c < 8; c++) {
    if (c < 7) gload(c + 1);
    const float* ekb = &EkL[c & 1][lane * 64];
#pragma unroll 4
    for (int g = 0; g < 16; g++) {
      float4 ek = *(const float4*)(ekb + ((g ^ sw) << 2));
      float4 w = we4[c * 16 + g];
      float4 qa = qa4[c * 16 + g];
      float4 qb = qb4[c * 16 + g];
      {
        float a1 = fmaf(qa.x, ek.x, 1.f), b1 = fmaf(qa.y, ek.y, 1.f);
        float n1 = fmaf(w.y, a1, w.x * b1);
        accA = fmaf(n1, __builtin_amdgcn_rcpf(a1 * b1), accA);
        float a2 = fmaf(qa.z, ek.z, 1.f), b2 = fmaf(qa.w, ek.w, 1.f);
        float n2 = fmaf(w.w, a2, w.z * b2);
        accA = fmaf(n2, __builtin_amdgcn_rcpf(a2 * b2), accA);
      }
      {
        float a1 = fmaf(qb.x, ek.x, 1.f), b1 = fmaf(qb.y, ek.y, 1.f);
        float n1 = fmaf(w.y, a1, w.x * b1);
        accB = fmaf(n1, __builtin_amdgcn_rcpf(a1 * b1), accB);
        float a2 = fmaf(qb.z, ek.z, 1.f), b2 = fmaf(qb.w, ek.w, 1.f);
        float n2 = fmaf(w.w, a2, w.z * b2);
        accB = fmaf(n2, __builtin_amdgcn_rcpf(a2 * b2), accB);
      }
    }
    if (c < 7) {
      __syncthreads();
      lwrite((c + 1) & 1);
      __syncthreads();
    }
  }

  sraw[(size_t)(q0g + qA + 0) * kS + s0 + lane] = fmaf(-2.f, accA, wsum);
  sraw[(size_t)(q0g + qA + 1) * kS + s0 + lane] = fmaf(-2.f, accB, wsum);
}

// ---------------------------------------------------------------------------
// Fused softmax + context + reduce.
// grid = 256: bid = qc*16 + b*4 + hc  (qc 0..15 -> 4 q rows; hc 0..3 ->
// 128 h). qc stride-16 => all 16 qc-blocks of a (b,hc) share an XCD ->
// value slice (512KB) L2-resident, read once from HBM.
// Phase A: wave wv softmaxes row (b*64+qc*4+wv) fully in registers
// (16 f32/lane), writes normalized weights to LDS wt[4][1024]; hc==0
// blocks also write wout. Phase B: wave wv accumulates s in
// [wv*256,(wv+1)*256) for 4 q x 128 h (lane = float2 of h); LDS reduce
// across waves; write ctx.
// ---------------------------------------------------------------------------
__global__ __launch_bounds__(256) void ctx_fused(
    const float* __restrict__ sraw, const float* __restrict__ value,
    float* __restrict__ wout, float* __restrict__ ctx) {
  __shared__ __align__(16) float wt[4][1024];
  __shared__ __align__(16) float parts[4][4][128];
  const int bid = blockIdx.x;
  const int qc = bid >> 4, b = (bid >> 2) & 3, hc = bid & 3;
  const int t = threadIdx.x, wv = t >> 6, lane = t & 63;
  const int grow = b * kQ + qc * 4 + wv;

  // Phase A: softmax of row grow (full row in wave registers).
  const float4* row4 = (const float4*)(sraw + (size_t)grow * kS);
  float4 v[4];
#pragma unroll
  for (int j = 0; j < 4; j++) v[j] = row4[lane + 64 * j];
  float m = -1e30f;
#pragma unroll
  for (int j = 0; j < 4; j++)
    m = fmaxf(m, fmaxf(fmaxf(v[j].x, v[j].y), fmaxf(v[j].z, v[j].w)));
#pragma unroll
  for (int off = 32; off; off >>= 1) m = fmaxf(m, __shfl_xor(m, off));
  float sum = 0.f;
#pragma unroll
  for (int j = 0; j < 4; j++) {
    v[j].x = __expf(v[j].x - m); v[j].y = __expf(v[j].y - m);
    v[j].z = __expf(v[j].z - m); v[j].w = __expf(v[j].w - m);
    sum += v[j].x + v[j].y + v[j].z + v[j].w;
  }
#pragma unroll
  for (int off = 32; off; off >>= 1) sum += __shfl_xor(sum, off);
  const float inv = 1.f / sum;
  float4* wrow = (float4*)&wt[wv][0];
  float4* gw = (float4*)(wout + (size_t)grow * kS);
#pragma unroll
  for (int j = 0; j < 4; j++) {
    v[j].x *= inv; v[j].y *= inv; v[j].z *= inv; v[j].w *= inv;
    wrow[lane + 64 * j] = v[j];
    if (hc == 0) gw[lane + 64 * j] = v[j];
  }
  __syncthreads();

  // Phase B: context accumulate. lane -> float2 of h; wave -> s quarter.
  const float* vbase =
      value + ((size_t)b * kS + wv * 256) * kH + hc * 128 + lane * 2;
  float2 acc[4];
#pragma unroll
  for (int q = 0; q < 4; q++) acc[q] = {0.f, 0.f};
#pragma unroll 2
  for (int s4 = 0; s4 < 64; s4++) {
    float4 wq[4];
#pragma unroll
    for (int q = 0; q < 4; q++)
      wq[q] = *(const float4*)&wt[q][wv * 256 + s4 * 4];
#pragma unroll
    for (int u = 0; u < 4; u++) {
      const float2 vv = *(const float2*)(vbase + (size_t)(s4 * 4 + u) * kH);
      const float w0 = ((const float*)&wq[0])[u];
      const float w1 = ((const float*)&wq[1])[u];
      const float w2 = ((const float*)&wq[2])[u];
      const float w3 = ((const float*)&wq[3])[u];
      acc[0].x = fmaf(w0, vv.x, acc[0].x); acc[0].y = fmaf(w0, vv.y, acc[0].y);
      acc[1].x = fmaf(w1, vv.x, acc[1].x); acc[1].y = fmaf(w1, vv.y, acc[1].y);
      acc[2].x = fmaf(w2, vv.x, acc[2].x); acc[2].y = fmaf(w2, vv.y, acc[2].y);
      acc[3].x = fmaf(w3, vv.x, acc[3].x); acc[3].y = fmaf(w3, vv.y, acc[3].y);
    }
  }
#pragma unroll
  for (int q = 0; q < 4; q++)
    *(float2*)&parts[wv][q][lane * 2] = acc[q];
  __syncthreads();

  // Cross-wave reduce: thread t -> q = t>>6, h-pair = t&63.
  const int q = t >> 6, hp = t & 63;
  float2 r = {0.f, 0.f};
#pragma unroll
  for (int w = 0; w < 4; w++) {
    const float2 p2 = *(const float2*)&parts[w][q][hp * 2];
    r.x += p2.x; r.y += p2.y;
  }
  *(float2*)(ctx + (size_t)(b * kQ + qc * 4 + q) * kH + hc * 128 + hp * 2) = r;
}

extern "C" void kernel_launch(void* const* d_in, const int* in_sizes, int n_in,
                              void* d_out, int out_size, void* d_ws,
                              size_t ws_size, hipStream_t stream) {
  const float* query = (const float*)d_in[0];
  const float* key_  = (const float*)d_in[1];
  const float* value = (const float*)d_in[2];
  const float* Wq    = (const float*)d_in[3];
  const float* bq    = (const float*)d_in[4];
  const float* Wk    = (const float*)d_in[5];
  const float* bk    = (const float*)d_in[6];
  const float* we    = (const float*)d_in[7];
  // be (d_in[8]) cancels in softmax.

  float* ctx  = (float*)d_out;                         // [256*512]
  float* wout = (float*)d_out + (size_t)kB * kQ * kH;  // [256*1024]

  float* Eq = (float*)d_ws;                            // 512 KB
  float* Ek = Eq + (size_t)kB * kQ * kH;               // 8 MB
  unsigned short* Bhi =
      (unsigned short*)((char*)d_ws + (size_t)(kB * kQ * kH + kB * kS * kH) * 4);
  unsigned short* Blo = Bhi + (size_t)2 * 8 * 16 * 256 * 8;  // +1MB
  unsigned short* Xhi = Blo + (size_t)2 * 8 * 16 * 256 * 8;  // +1MB
  unsigned short* Xlo = Xhi + (size_t)34 * 16 * 512 * 8;     // +4.25MB
  float* sraw = (float*)(Xlo + (size_t)34 * 16 * 512 * 8);   // +4.25MB -> 1MB

  convert_all<<<800, 256, 0, stream>>>(Wk, Wq, key_, query, Bhi, Blo, Xhi, Xlo);
  proj_mfma<<<dim3(8, 34), 512, 0, stream>>>(Xhi, Xlo, Bhi, Blo, bk, bq, Ek, Eq);
  score_kernel<<<dim3(8, 16, 4), 256, 0, stream>>>(Eq, Ek, we, sraw);
  ctx_fused<<<256, 256, 0, stream>>>(sraw, value, wout, ctx);
}